// Round 10
// baseline (320.454 us; speedup 1.0000x reference)
//
#include <hip/hip_runtime.h>
#include <hip/hip_bf16.h>

typedef __attribute__((ext_vector_type(8))) short bf16x8;
typedef __attribute__((ext_vector_type(4))) float f32x4;

// ---------------- helpers ----------------
__device__ inline ushort f2bf(float f) {  // RNE float->bf16
  uint u = __float_as_uint(f);
  return (ushort)((u + 0x7FFFu + ((u >> 16) & 1u)) >> 16);
}

// ---------------- weight pack (f32 [K][N] -> bf16 [N][K]) + starts + tile list ----------------
__global__ __launch_bounds__(256) void pack_weights(
    const float* __restrict__ qkv_w, const float* __restrict__ out_w,
    const float* __restrict__ ff1_w, const float* __restrict__ ff2_w,
    const float* __restrict__ b1_w, const float* __restrict__ lat_w,
    short* __restrict__ qkv_t, short* __restrict__ out_t,
    short* __restrict__ ff1_t, short* __restrict__ ff2_t,
    short* __restrict__ b1_t, short* __restrict__ lat_t,
    const int* __restrict__ batch, int* __restrict__ starts, int* __restrict__ meta) {
  int t = blockIdx.x;
  if (t == 3112) {  // graph boundaries + graph-aligned 16-row tile list
    for (int i = threadIdx.x; i < 2048; i += 256) {
      int b = batch[i];
      if (i == 0) {
        for (int g = 0; g <= b; ++g) starts[g] = 0;
      } else {
        int bp = batch[i - 1];
        for (int g = bp + 1; g <= b; ++g) starts[g] = i;
      }
      if (i == 2047) {
        for (int g = b + 1; g <= 16; ++g) starts[g] = 2048;
      }
    }
    __syncthreads();
    if (threadIdx.x == 0) {
      int nt = 0;
      for (int g = 0; g < 16; ++g) {
        const int js = starts[g], je = starts[g + 1];
        for (int q0 = js; q0 < je; q0 += 16) {
          meta[1 + nt * 3] = q0;
          meta[2 + nt * 3] = js;
          meta[3 + nt * 3] = je;
          ++nt;
        }
      }
      meta[0] = nt;
    }
    return;
  }
  const float* src;
  short* dst;
  int Kd, Nd, rem;
  if (t < 768) {
    int l = t / 192; rem = t % 192; Kd = 256; Nd = 768;
    src = qkv_w + (size_t)l * Kd * Nd; dst = qkv_t + (size_t)l * Nd * Kd;
  } else if (t < 1024) {
    t -= 768; int l = t / 64; rem = t % 64; Kd = 256; Nd = 256;
    src = out_w + (size_t)l * Kd * Nd; dst = out_t + (size_t)l * Nd * Kd;
  } else if (t < 2048) {
    t -= 1024; int l = t / 256; rem = t % 256; Kd = 256; Nd = 1024;
    src = ff1_w + (size_t)l * Kd * Nd; dst = ff1_t + (size_t)l * Nd * Kd;
  } else if (t < 3072) {
    t -= 2048; int l = t / 256; rem = t % 256; Kd = 1024; Nd = 256;
    src = ff2_w + (size_t)l * Kd * Nd; dst = ff2_t + (size_t)l * Nd * Kd;
  } else if (t < 3104) {
    rem = t - 3072; Kd = 256; Nd = 128; src = b1_w; dst = b1_t;
  } else {
    rem = t - 3104; Kd = 256; Nd = 32; src = lat_w; dst = lat_t;
  }
  const int ntn = Nd / 32;
  const int kt = rem / ntn, nt = rem % ntn;

  __shared__ float tile[32][33];
  const int tx = threadIdx.x & 31, ty = threadIdx.x >> 5;
#pragma unroll
  for (int r = 0; r < 4; ++r) {
    int k = kt * 32 + ty + r * 8;
    tile[ty + r * 8][tx] = src[(size_t)k * Nd + nt * 32 + tx];
  }
  __syncthreads();
#pragma unroll
  for (int r = 0; r < 4; ++r) {
    int n = nt * 32 + ty + r * 8;
    dst[(size_t)n * Kd + kt * 32 + tx] = (short)f2bf(tile[tx][ty + r * 8]);
  }
}

// ---------------- input projection: h = x @ Wi + bi (K=16); writes f32 + bf16 ----------------
__global__ __launch_bounds__(256) void inproj_kernel(
    const float* __restrict__ x, const float* __restrict__ Wi,
    const float* __restrict__ bi, float* __restrict__ h, short* __restrict__ hb) {
  __shared__ float xs[16];
  const int i = blockIdx.x, j = threadIdx.x;
  if (j < 16) xs[j] = x[(size_t)i * 16 + j];
  __syncthreads();
  float acc = bi[j];
#pragma unroll
  for (int k = 0; k < 16; ++k) acc += xs[k] * Wi[k * 256 + j];
  h[(size_t)i * 256 + j] = acc;
  hb[(size_t)i * 256 + j] = (short)f2bf(acc);
}

// ---------------- MFMA bf16 GEMM (LDS-staged, BK=128), bf16 out ----------------
// VT=1: for bn in [8,12) (qkv V columns 512..767), also write V^T [256][2048]
// via LDS transpose + coalesced 128B row stores.
template <int ACT, int VT>
__global__ __launch_bounds__(256) void gemm_bf16(
    const short* __restrict__ A, const short* __restrict__ Bt,
    const float* __restrict__ bias, short* __restrict__ Cb,
    short* __restrict__ vtg, int N, int K) {
  __shared__ short As[64 * 128];
  __shared__ short Bs[64 * 128];

  const int t = threadIdx.x;
  const int bm = blockIdx.y, bn = blockIdx.x;
  const int srow = t >> 2, sq = t & 3;
  const int lane = t & 63, wid = t >> 6;
  const int wr = wid >> 1, wc = wid & 1;
  const int fr = lane & 15, fs = lane >> 4;
  const int rx = srow & 7;

  f32x4 acc[2][2];
#pragma unroll
  for (int m = 0; m < 2; ++m)
#pragma unroll
    for (int n = 0; n < 2; ++n) acc[m][n] = (f32x4){0.f, 0.f, 0.f, 0.f};

  const short* ap = A + (size_t)(bm * 64 + srow) * K;
  const int ng = bn * 64 + srow;
  const short* bp = Bt + (size_t)ng * K;
  const int ar0 = wr * 32 + fr, ar1 = ar0 + 16;
  const int bc0 = wc * 32 + fr, bc1 = bc0 + 16;

  for (int k0 = 0; k0 < K; k0 += 128) {
    bf16x8 av[4], bv[4];
#pragma unroll
    for (int i = 0; i < 4; ++i) av[i] = *(const bf16x8*)(ap + k0 + (sq * 4 + i) * 8);
    if (ng < N) {
#pragma unroll
      for (int i = 0; i < 4; ++i) bv[i] = *(const bf16x8*)(bp + k0 + (sq * 4 + i) * 8);
    } else {
#pragma unroll
      for (int i = 0; i < 4; ++i) bv[i] = (bf16x8){0, 0, 0, 0, 0, 0, 0, 0};
    }
    __syncthreads();
#pragma unroll
    for (int i = 0; i < 4; ++i) {
      const int s = sq * 4 + i;
      *(bf16x8*)(As + srow * 128 + ((s ^ rx) * 8)) = av[i];
      *(bf16x8*)(Bs + srow * 128 + ((s ^ rx) * 8)) = bv[i];
    }
    __syncthreads();
#pragma unroll
    for (int ks = 0; ks < 4; ++ks) {
      const int u = ks * 4 + fs;
      bf16x8 a0 = *(const bf16x8*)(As + ar0 * 128 + ((u ^ (ar0 & 7)) * 8));
      bf16x8 a1 = *(const bf16x8*)(As + ar1 * 128 + ((u ^ (ar1 & 7)) * 8));
      bf16x8 b0 = *(const bf16x8*)(Bs + bc0 * 128 + ((u ^ (bc0 & 7)) * 8));
      bf16x8 b1 = *(const bf16x8*)(Bs + bc1 * 128 + ((u ^ (bc1 & 7)) * 8));
      acc[0][0] = __builtin_amdgcn_mfma_f32_16x16x32_bf16(a0, b0, acc[0][0], 0, 0, 0);
      acc[0][1] = __builtin_amdgcn_mfma_f32_16x16x32_bf16(a0, b1, acc[0][1], 0, 0, 0);
      acc[1][0] = __builtin_amdgcn_mfma_f32_16x16x32_bf16(a1, b0, acc[1][0], 0, 0, 0);
      acc[1][1] = __builtin_amdgcn_mfma_f32_16x16x32_bf16(a1, b1, acc[1][1], 0, 0, 0);
    }
  }

#pragma unroll
  for (int n = 0; n < 2; ++n) {
    const int col = bn * 64 + wc * 32 + n * 16 + fr;
    if (col < N) {
      const float bvv = bias[col];
#pragma unroll
      for (int m = 0; m < 2; ++m) {
        const int rbase = bm * 64 + wr * 32 + m * 16 + fs * 4;
#pragma unroll
        for (int j = 0; j < 4; ++j) {
          float v = acc[m][n][j] + bvv;
          if (ACT == 1) v = fmaxf(v, 0.f);
          Cb[(size_t)(rbase + j) * N + col] = (short)f2bf(v);
        }
      }
    }
  }

  // coalesced V^T epilogue for qkv tiles covering cols [512,768)
  if (VT && bn >= 8) {
    short* tr = As;  // reuse LDS: [64][68]
    __syncthreads();
#pragma unroll
    for (int n = 0; n < 2; ++n) {
      const int c = wc * 32 + n * 16 + fr;
      const float bvv = bias[bn * 64 + c];
#pragma unroll
      for (int m = 0; m < 2; ++m)
#pragma unroll
        for (int j = 0; j < 4; ++j) {
          const int r = wr * 32 + m * 16 + fs * 4 + j;
          tr[c * 68 + r] = (short)f2bf(acc[m][n][j] + bvv);
        }
    }
    __syncthreads();
    const int tx = t & 63, ty = t >> 6;
    const int d0 = bn * 64 - 512, rb = bm * 64;
#pragma unroll
    for (int r = 0; r < 16; ++r) {
      const int d = ty * 16 + r;
      vtg[(size_t)(d0 + d) * 2048 + rb + tx] = tr[d * 68 + tx];
    }
  }
}

// ---------------- attention: one independent wave per (16-row graph-aligned q-tile, head) ----------------
// No LDS, no barriers. Swapped QK^T (mfma(K,Q) -> S^T): lane (fr,fs) holds
// P[q=fr][j=jbase+jt*16+fs*4+jj]; softmax over j = reg-reduce + shfl_xor(16,32).
// That layout IS the PV A-fragment; V^T global loads use the same k->j map.
__global__ __launch_bounds__(256) void attn_direct(
    const short* __restrict__ qkv, const short* __restrict__ vtg,
    const int* __restrict__ meta, short* __restrict__ out) {
  const int wid = blockIdx.x * 4 + (threadIdx.x >> 6);
  const int tile = wid >> 3, h = wid & 7;
  if (tile >= meta[0]) return;
  const int lane = threadIdx.x & 63;
  const int fr = lane & 15, fs = lane >> 4;
  const int q0 = meta[1 + tile * 3];
  const int js = meta[2 + tile * 3];
  const int je = meta[3 + tile * 3];
  const int jbase = js & ~15;
  const int njt = (je - jbase + 15) >> 4;
  const float scale = 0.17677669529663687f;  // 1/sqrt(32)

  const int qrow = min(q0 + fr, 2047);
  const bf16x8 qf = *(const bf16x8*)(qkv + (size_t)qrow * 768 + h * 32 + fs * 8);
  const int jeq = (q0 + fr < je) ? je : 0;

  f32x4 s[16];
#pragma unroll
  for (int jt = 0; jt < 16; ++jt)
    s[jt] = (f32x4){-3.0e38f, -3.0e38f, -3.0e38f, -3.0e38f};

#pragma unroll
  for (int jt = 0; jt < 16; ++jt) {
    if (jt < njt) {
      const int krow = min(jbase + jt * 16 + fr, 2047);
      const bf16x8 kf = *(const bf16x8*)(qkv + (size_t)krow * 768 + 256 + h * 32 + fs * 8);
      s[jt] = __builtin_amdgcn_mfma_f32_16x16x32_bf16(
          kf, qf, (f32x4){0.f, 0.f, 0.f, 0.f}, 0, 0, 0);
    }
  }
  float mx = -3.0e38f;
#pragma unroll
  for (int jt = 0; jt < 16; ++jt) {
    if (jt < njt) {
#pragma unroll
      for (int jj = 0; jj < 4; ++jj) {
        const int j = jbase + jt * 16 + fs * 4 + jj;
        const bool valid = (j >= js) && (j < jeq);
        s[jt][jj] = valid ? s[jt][jj] * scale : -3.0e38f;
        mx = fmaxf(mx, s[jt][jj]);
      }
    }
  }
  mx = fmaxf(mx, __shfl_xor(mx, 16, 64));
  mx = fmaxf(mx, __shfl_xor(mx, 32, 64));
  float l = 0.f;
#pragma unroll
  for (int jt = 0; jt < 16; ++jt) {
#pragma unroll
    for (int jj = 0; jj < 4; ++jj) {
      const float p = __expf(s[jt][jj] - mx);
      s[jt][jj] = p;
      l += p;
    }
  }
  l += __shfl_xor(l, 16, 64);
  l += __shfl_xor(l, 32, 64);

  f32x4 oa[2];
  oa[0] = (f32x4){0.f, 0.f, 0.f, 0.f};
  oa[1] = (f32x4){0.f, 0.f, 0.f, 0.f};
#pragma unroll
  for (int p2 = 0; p2 < 8; ++p2) {
    if (p2 * 2 < njt) {
      bf16x8 pa;
      pa[0] = (short)f2bf(s[p2 * 2][0]);     pa[1] = (short)f2bf(s[p2 * 2][1]);
      pa[2] = (short)f2bf(s[p2 * 2][2]);     pa[3] = (short)f2bf(s[p2 * 2][3]);
      pa[4] = (short)f2bf(s[p2 * 2 + 1][0]); pa[5] = (short)f2bf(s[p2 * 2 + 1][1]);
      pa[6] = (short)f2bf(s[p2 * 2 + 1][2]); pa[7] = (short)f2bf(s[p2 * 2 + 1][3]);
      const int jb0 = min(jbase + p2 * 32 + fs * 4, 2044);
      const int jb1 = min(jbase + p2 * 32 + 16 + fs * 4, 2044);
#pragma unroll
      for (int nt = 0; nt < 2; ++nt) {
        const short* vrow = vtg + (size_t)(h * 32 + nt * 16 + fr) * 2048;
        const short4 v0 = *(const short4*)(vrow + jb0);
        const short4 v1 = *(const short4*)(vrow + jb1);
        bf16x8 vf;
        vf[0] = v0.x; vf[1] = v0.y; vf[2] = v0.z; vf[3] = v0.w;
        vf[4] = v1.x; vf[5] = v1.y; vf[6] = v1.z; vf[7] = v1.w;
        oa[nt] = __builtin_amdgcn_mfma_f32_16x16x32_bf16(pa, vf, oa[nt], 0, 0, 0);
      }
    }
  }
#pragma unroll
  for (int jj = 0; jj < 4; ++jj) {
    const float lq = __shfl(l, fs * 4 + jj, 64);
    const int node = q0 + fs * 4 + jj;
    if (node < je) {
      const float inv = 1.f / lq;
      out[(size_t)node * 256 + h * 32 + fr] = (short)f2bf(oa[0][jj] * inv);
      out[(size_t)node * 256 + h * 32 + 16 + fr] = (short)f2bf(oa[1][jj] * inv);
    }
  }
}

// ---------------- 16-row GEMM (direct L2 fragment loads) + fused residual + LN ----------------
// Block = 16 rows x 256 cols. Wave w owns cols w*64..w*64+63. Residual from hio (f32);
// writes LN result to hio (f32) + hbo (bf16).
__global__ __launch_bounds__(256) void gemm_ln(
    const short* __restrict__ A, const short* __restrict__ Bt,
    const float* __restrict__ bias, const float* __restrict__ lns,
    const float* __restrict__ lnb, float* __restrict__ hio,
    short* __restrict__ hbo, int K) {
  __shared__ float red[128];
  const int t = threadIdx.x, lane = t & 63, w = t >> 6;
  const int fr = lane & 15, fs = lane >> 4;
  const int rb = blockIdx.x * 16;

  f32x4 acc[4];
#pragma unroll
  for (int n = 0; n < 4; ++n) acc[n] = (f32x4){0.f, 0.f, 0.f, 0.f};
  const short* ap = A + (size_t)(rb + fr) * K;
  const short* bp = Bt + (size_t)(w * 64 + fr) * K;
  for (int k0 = 0; k0 < K; k0 += 32) {
    const bf16x8 af = *(const bf16x8*)(ap + k0 + fs * 8);
#pragma unroll
    for (int n = 0; n < 4; ++n) {
      const bf16x8 bf = *(const bf16x8*)(bp + (size_t)n * 16 * K + k0 + fs * 8);
      acc[n] = __builtin_amdgcn_mfma_f32_16x16x32_bf16(af, bf, acc[n], 0, 0, 0);
    }
  }

  float d[4][4];
#pragma unroll
  for (int n = 0; n < 4; ++n) {
    const int col = w * 64 + n * 16 + fr;
    const float bv = bias[col];
#pragma unroll
    for (int j = 0; j < 4; ++j) {
      const int row = rb + fs * 4 + j;
      d[n][j] = acc[n][j] + bv + hio[(size_t)row * 256 + col];
    }
  }
  float ps[4], pq[4];
#pragma unroll
  for (int j = 0; j < 4; ++j) {
    ps[j] = d[0][j] + d[1][j] + d[2][j] + d[3][j];
    pq[j] = d[0][j] * d[0][j] + d[1][j] * d[1][j] + d[2][j] * d[2][j] + d[3][j] * d[3][j];
#pragma unroll
    for (int m = 1; m <= 8; m <<= 1) {
      ps[j] += __shfl_xor(ps[j], m, 64);
      pq[j] += __shfl_xor(pq[j], m, 64);
    }
  }
  if (fr == 0) {
#pragma unroll
    for (int j = 0; j < 4; ++j) {
      red[w * 16 + fs * 4 + j] = ps[j];
      red[64 + w * 16 + fs * 4 + j] = pq[j];
    }
  }
  __syncthreads();
#pragma unroll
  for (int j = 0; j < 4; ++j) {
    const int row = fs * 4 + j;
    const float S = red[row] + red[16 + row] + red[32 + row] + red[48 + row];
    const float Q = red[64 + row] + red[80 + row] + red[96 + row] + red[112 + row];
    const float mean = S * (1.f / 256.f);
    const float var = Q * (1.f / 256.f) - mean * mean;
    const float rs = rsqrtf(var + 1e-5f);
#pragma unroll
    for (int n = 0; n < 4; ++n) {
      const int col = w * 64 + n * 16 + fr;
      const float o = (d[n][j] - mean) * rs * lns[col] + lnb[col];
      hio[(size_t)(rb + row) * 256 + col] = o;
      hbo[(size_t)(rb + row) * 256 + col] = (short)f2bf(o);
    }
  }
}

// ---------------- beta head fully fused: sigmoid(relu(h@W1+b1)@w2+b2), 16 rows/block ----------------
__global__ __launch_bounds__(256) void gemm_beta(
    const short* __restrict__ A, const short* __restrict__ Bt,
    const float* __restrict__ b1b, const float* __restrict__ w2,
    const float* __restrict__ b2b, float* __restrict__ beta) {
  __shared__ float red[64];
  const int t = threadIdx.x, lane = t & 63, w = t >> 6;
  const int fr = lane & 15, fs = lane >> 4;
  const int rb = blockIdx.x * 16;

  f32x4 acc[2];
  acc[0] = (f32x4){0.f, 0.f, 0.f, 0.f};
  acc[1] = (f32x4){0.f, 0.f, 0.f, 0.f};
  const short* ap = A + (size_t)(rb + fr) * 256;
  const short* bp = Bt + (size_t)(w * 32 + fr) * 256;
  for (int k0 = 0; k0 < 256; k0 += 32) {
    const bf16x8 af = *(const bf16x8*)(ap + k0 + fs * 8);
#pragma unroll
    for (int n = 0; n < 2; ++n) {
      const bf16x8 bf = *(const bf16x8*)(bp + (size_t)n * 16 * 256 + k0 + fs * 8);
      acc[n] = __builtin_amdgcn_mfma_f32_16x16x32_bf16(af, bf, acc[n], 0, 0, 0);
    }
  }
  const int c0 = w * 32 + fr, c1 = c0 + 16;
  const float b0 = b1b[c0], b1 = b1b[c1];
  const float w0 = w2[c0], w1 = w2[c1];
  float part[4];
#pragma unroll
  for (int j = 0; j < 4; ++j) {
    const float d0 = fmaxf(acc[0][j] + b0, 0.f);
    const float d1 = fmaxf(acc[1][j] + b1, 0.f);
    part[j] = d0 * w0 + d1 * w1;
#pragma unroll
    for (int m = 1; m <= 8; m <<= 1) part[j] += __shfl_xor(part[j], m, 64);
  }
  if (fr == 0) {
#pragma unroll
    for (int j = 0; j < 4; ++j) red[w * 16 + fs * 4 + j] = part[j];
  }
  __syncthreads();
  if (t < 16) {
    const float S = red[t] + red[16 + t] + red[32 + t] + red[48 + t] + b2b[0];
    float sgm = 1.f / (1.f + __expf(-S));
    sgm = fminf(fmaxf(sgm, 1e-6f), 1.f - 1e-6f);
    beta[rb + t] = sgm;
  }
}

// ---------------- lat head: GEMM (N=32, K=256) + fused row-normalize ----------------
__global__ __launch_bounds__(256) void lat_kernel(
    const short* __restrict__ A, const short* __restrict__ Bt,
    const float* __restrict__ bias, float* __restrict__ out) {
  __shared__ short As[64 * 128];
  __shared__ short Bs[64 * 128];
  const int t = threadIdx.x;
  const int bm = blockIdx.x;
  const int srow = t >> 2, sq = t & 3;
  const int lane = t & 63, w = t >> 6;
  const int fr = lane & 15, fs = lane >> 4;
  const int rx = srow & 7;

  f32x4 acc[2];
  acc[0] = (f32x4){0.f, 0.f, 0.f, 0.f};
  acc[1] = (f32x4){0.f, 0.f, 0.f, 0.f};
  const short* ap = A + (size_t)(bm * 64 + srow) * 256;
  const short* bp = Bt + (size_t)srow * 256;
  const int ar = w * 16 + fr;

  for (int k0 = 0; k0 < 256; k0 += 128) {
    bf16x8 av[4], bv[4];
#pragma unroll
    for (int i = 0; i < 4; ++i) av[i] = *(const bf16x8*)(ap + k0 + (sq * 4 + i) * 8);
    if (srow < 32) {
#pragma unroll
      for (int i = 0; i < 4; ++i) bv[i] = *(const bf16x8*)(bp + k0 + (sq * 4 + i) * 8);
    } else {
#pragma unroll
      for (int i = 0; i < 4; ++i) bv[i] = (bf16x8){0, 0, 0, 0, 0, 0, 0, 0};
    }
    __syncthreads();
#pragma unroll
    for (int i = 0; i < 4; ++i) {
      const int s = sq * 4 + i;
      *(bf16x8*)(As + srow * 128 + ((s ^ rx) * 8)) = av[i];
      *(bf16x8*)(Bs + srow * 128 + ((s ^ rx) * 8)) = bv[i];
    }
    __syncthreads();
#pragma unroll
    for (int ks = 0; ks < 4; ++ks) {
      const int u = ks * 4 + fs;
      bf16x8 a0 = *(const bf16x8*)(As + ar * 128 + ((u ^ (ar & 7)) * 8));
      bf16x8 b0 = *(const bf16x8*)(Bs + fr * 128 + ((u ^ (fr & 7)) * 8));
      bf16x8 b1 = *(const bf16x8*)(Bs + (16 + fr) * 128 + ((u ^ ((16 + fr) & 7)) * 8));
      acc[0] = __builtin_amdgcn_mfma_f32_16x16x32_bf16(a0, b0, acc[0], 0, 0, 0);
      acc[1] = __builtin_amdgcn_mfma_f32_16x16x32_bf16(a0, b1, acc[1], 0, 0, 0);
    }
  }
  const float b0v = bias[fr], b1v = bias[16 + fr];
#pragma unroll
  for (int j = 0; j < 4; ++j) {
    const int row = bm * 64 + w * 16 + fs * 4 + j;
    float v0 = acc[0][j] + b0v;
    float v1 = acc[1][j] + b1v;
    float ss = v0 * v0 + v1 * v1;
    ss += __shfl_xor(ss, 1, 64);
    ss += __shfl_xor(ss, 2, 64);
    ss += __shfl_xor(ss, 4, 64);
    ss += __shfl_xor(ss, 8, 64);
    const float inv = 5.656854249492381f / fmaxf(sqrtf(ss), 1e-12f);
    out[(size_t)row * 32 + fr] = v0 * inv;
    out[(size_t)row * 32 + 16 + fr] = v1 * inv;
  }
}

// ---------------- launch ----------------
extern "C" void kernel_launch(void* const* d_in, const int* in_sizes, int n_in,
                              void* d_out, int out_size, void* d_ws, size_t ws_size,
                              hipStream_t stream) {
  const int N = 2048, D = 256, FF = 1024, L = 4;

  const float* x     = (const float*)d_in[0];
  const int*   batch = (const int*)d_in[2];
  const float* Wi    = (const float*)d_in[3];
  const float* bi    = (const float*)d_in[4];
  const float* qkv_w = (const float*)d_in[5];
  const float* qkv_b = (const float*)d_in[6];
  const float* out_w = (const float*)d_in[7];
  const float* out_b = (const float*)d_in[8];
  const float* ff1_w = (const float*)d_in[9];
  const float* ff1_b = (const float*)d_in[10];
  const float* ff2_w = (const float*)d_in[11];
  const float* ff2_b = (const float*)d_in[12];
  const float* ln1_s = (const float*)d_in[13];
  const float* ln1_b = (const float*)d_in[14];
  const float* ln2_s = (const float*)d_in[15];
  const float* ln2_b = (const float*)d_in[16];
  const float* lat_w = (const float*)d_in[17];
  const float* lat_b = (const float*)d_in[18];
  const float* b1_w  = (const float*)d_in[19];
  const float* b1_b  = (const float*)d_in[20];
  const float* b2_w  = (const float*)d_in[21];
  const float* b2_b  = (const float*)d_in[22];

  float* ws = (float*)d_ws;
  float* h      = ws;                              // N*D f32
  int*  starts  = (int*)(h + (size_t)N * D);       // 32 ints
  int*  meta    = starts + 32;                     // 448 ints
  short* hb     = (short*)(meta + 448);            // N*D bf16
  short* qkvb   = hb + (size_t)N * D;              // N*3D bf16
  short* attnb  = qkvb + (size_t)N * 3 * D;        // N*D bf16
  short* ffb    = attnb + (size_t)N * D;           // N*FF bf16
  short* vtg    = ffb + (size_t)N * FF;            // 256*2048 bf16 (V^T per layer)
  short* qkv_t  = vtg + (size_t)256 * 2048;
  short* out_t  = qkv_t + (size_t)L * 768 * 256;
  short* ff1_t  = out_t + (size_t)L * 256 * 256;
  short* ff2_t  = ff1_t + (size_t)L * 1024 * 256;
  short* b1_t   = ff2_t + (size_t)L * 256 * 1024;
  short* lat_t  = b1_t + (size_t)128 * 256;

  float* beta_out = (float*)d_out;
  float* lat_out  = beta_out + N;

  pack_weights<<<3113, 256, 0, stream>>>(qkv_w, out_w, ff1_w, ff2_w, b1_w, lat_w,
                                         qkv_t, out_t, ff1_t, ff2_t, b1_t, lat_t,
                                         batch, starts, meta);
  inproj_kernel<<<N, 256, 0, stream>>>(x, Wi, bi, h, hb);

  for (int l = 0; l < L; ++l) {
    // qkv = h @ qkv_w + b -> bf16 (+ coalesced V^T epilogue)
    gemm_bf16<0, 1><<<dim3(12, 32), 256, 0, stream>>>(
        hb, qkv_t + (size_t)l * 768 * 256, qkv_b + (size_t)l * 768,
        qkvb, vtg, 768, 256);
    // attention (independent waves)
    attn_direct<<<288, 256, 0, stream>>>(qkvb, vtg, meta, attnb);
    // out-proj + residual + LN1 fused
    gemm_ln<<<128, 256, 0, stream>>>(attnb, out_t + (size_t)l * 256 * 256,
                                     out_b + (size_t)l * 256, ln1_s + (size_t)l * D,
                                     ln1_b + (size_t)l * D, h, hb, 256);
    // ff1 = relu(h @ ff1_w + b) -> bf16
    gemm_bf16<1, 0><<<dim3(16, 32), 256, 0, stream>>>(
        hb, ff1_t + (size_t)l * FF * 256, ff1_b + (size_t)l * FF,
        ffb, nullptr, 1024, 256);
    // ff2 + residual + LN2 fused (K=1024)
    gemm_ln<<<128, 256, 0, stream>>>(ffb, ff2_t + (size_t)l * 256 * FF,
                                     ff2_b + (size_t)l * 256, ln2_s + (size_t)l * D,
                                     ln2_b + (size_t)l * D, h, hb, 1024);
  }

  lat_kernel<<<N / 64, 256, 0, stream>>>(hb, lat_t, lat_b, lat_out);
  gemm_beta<<<128, 256, 0, stream>>>(hb, b1_t, b1_b, b2_w, b2_b, beta_out);
}

// Round 11
// 213.635 us; speedup vs baseline: 1.5000x; 1.5000x over previous
//
#include <hip/hip_runtime.h>
#include <hip/hip_bf16.h>

typedef __attribute__((ext_vector_type(8))) short bf16x8;
typedef __attribute__((ext_vector_type(4))) float f32x4;

// ---------------- helpers ----------------
__device__ inline float wave_sum64(float v) {
#pragma unroll
  for (int m = 32; m >= 1; m >>= 1) v += __shfl_xor(v, m, 64);
  return v;
}
__device__ inline ushort f2bf(float f) {  // RNE float->bf16
  uint u = __float_as_uint(f);
  return (ushort)((u + 0x7FFFu + ((u >> 16) & 1u)) >> 16);
}

// ---------------- weight pack (f32 [K][N] -> bf16 [N][K]) + starts + tile list ----------------
__global__ __launch_bounds__(256) void pack_weights(
    const float* __restrict__ qkv_w, const float* __restrict__ out_w,
    const float* __restrict__ ff1_w, const float* __restrict__ ff2_w,
    const float* __restrict__ b1_w, const float* __restrict__ lat_w,
    short* __restrict__ qkv_t, short* __restrict__ out_t,
    short* __restrict__ ff1_t, short* __restrict__ ff2_t,
    short* __restrict__ b1_t, short* __restrict__ lat_t,
    const int* __restrict__ batch, int* __restrict__ starts, int* __restrict__ meta) {
  int t = blockIdx.x;
  if (t == 3112) {  // graph boundaries + graph-aligned 16-row tile list
    for (int i = threadIdx.x; i < 2048; i += 256) {
      int b = batch[i];
      if (i == 0) {
        for (int g = 0; g <= b; ++g) starts[g] = 0;
      } else {
        int bp = batch[i - 1];
        for (int g = bp + 1; g <= b; ++g) starts[g] = i;
      }
      if (i == 2047) {
        for (int g = b + 1; g <= 16; ++g) starts[g] = 2048;
      }
    }
    __syncthreads();
    if (threadIdx.x == 0) {
      int nt = 0;
      for (int g = 0; g < 16; ++g) {
        const int js = starts[g], je = starts[g + 1];
        for (int q0 = js; q0 < je; q0 += 16) {
          meta[1 + nt * 3] = q0;
          meta[2 + nt * 3] = js;
          meta[3 + nt * 3] = je;
          ++nt;
        }
      }
      meta[0] = nt;
    }
    return;
  }
  const float* src;
  short* dst;
  int Kd, Nd, rem;
  if (t < 768) {
    int l = t / 192; rem = t % 192; Kd = 256; Nd = 768;
    src = qkv_w + (size_t)l * Kd * Nd; dst = qkv_t + (size_t)l * Nd * Kd;
  } else if (t < 1024) {
    t -= 768; int l = t / 64; rem = t % 64; Kd = 256; Nd = 256;
    src = out_w + (size_t)l * Kd * Nd; dst = out_t + (size_t)l * Nd * Kd;
  } else if (t < 2048) {
    t -= 1024; int l = t / 256; rem = t % 256; Kd = 256; Nd = 1024;
    src = ff1_w + (size_t)l * Kd * Nd; dst = ff1_t + (size_t)l * Nd * Kd;
  } else if (t < 3072) {
    t -= 2048; int l = t / 256; rem = t % 256; Kd = 1024; Nd = 256;
    src = ff2_w + (size_t)l * Kd * Nd; dst = ff2_t + (size_t)l * Nd * Kd;
  } else if (t < 3104) {
    rem = t - 3072; Kd = 256; Nd = 128; src = b1_w; dst = b1_t;
  } else {
    rem = t - 3104; Kd = 256; Nd = 32; src = lat_w; dst = lat_t;
  }
  const int ntn = Nd / 32;
  const int kt = rem / ntn, nt = rem % ntn;

  __shared__ float tile[32][33];
  const int tx = threadIdx.x & 31, ty = threadIdx.x >> 5;
#pragma unroll
  for (int r = 0; r < 4; ++r) {
    int k = kt * 32 + ty + r * 8;
    tile[ty + r * 8][tx] = src[(size_t)k * Nd + nt * 32 + tx];
  }
  __syncthreads();
#pragma unroll
  for (int r = 0; r < 4; ++r) {
    int n = nt * 32 + ty + r * 8;
    dst[(size_t)n * Kd + kt * 32 + tx] = (short)f2bf(tile[tx][ty + r * 8]);
  }
}

// ---------------- input projection: h = x @ Wi + bi (K=16); writes f32 + bf16 ----------------
__global__ __launch_bounds__(256) void inproj_kernel(
    const float* __restrict__ x, const float* __restrict__ Wi,
    const float* __restrict__ bi, float* __restrict__ h, short* __restrict__ hb) {
  __shared__ float xs[16];
  const int i = blockIdx.x, j = threadIdx.x;
  if (j < 16) xs[j] = x[(size_t)i * 16 + j];
  __syncthreads();
  float acc = bi[j];
#pragma unroll
  for (int k = 0; k < 16; ++k) acc += xs[k] * Wi[k * 256 + j];
  h[(size_t)i * 256 + j] = acc;
  hb[(size_t)i * 256 + j] = (short)f2bf(acc);
}

// ---------------- MFMA bf16 GEMM, BK=128, split-K via blockIdx.z ----------------
// OUTBF=1 -> bf16 output (unsplit). OUTBF=0 -> f32 partial at Cf + bz*M*N.
// VT=1 (with OUTBF=1): for bn>=8 (qkv V cols 512..767) also write V^T [256][2048]
// via LDS transpose + coalesced 128B row stores.
template <int ACT, int OUTBF, int VT>
__global__ __launch_bounds__(256) void gemm_bf16(
    const short* __restrict__ A, const short* __restrict__ Bt,
    const float* __restrict__ bias, float* __restrict__ Cf, short* __restrict__ Cb,
    short* __restrict__ vtg, int M, int N, int K, int kpb) {
  __shared__ short As[64 * 128];
  __shared__ short Bs[64 * 128];

  const int t = threadIdx.x;
  const int bm = blockIdx.y, bn = blockIdx.x, bz = blockIdx.z;
  const int srow = t >> 2, sq = t & 3;
  const int lane = t & 63, wid = t >> 6;
  const int wr = wid >> 1, wc = wid & 1;
  const int fr = lane & 15, fs = lane >> 4;
  const int rx = srow & 7;

  f32x4 acc[2][2];
#pragma unroll
  for (int m = 0; m < 2; ++m)
#pragma unroll
    for (int n = 0; n < 2; ++n) acc[m][n] = (f32x4){0.f, 0.f, 0.f, 0.f};

  const int kbase = bz * kpb;
  const short* ap = A + (size_t)(bm * 64 + srow) * K + kbase;
  const int ng = bn * 64 + srow;
  const short* bp = Bt + (size_t)ng * K + kbase;
  const int ar0 = wr * 32 + fr, ar1 = ar0 + 16;
  const int bc0 = wc * 32 + fr, bc1 = bc0 + 16;

  for (int k0 = 0; k0 < kpb; k0 += 128) {
    bf16x8 av[4], bv[4];
#pragma unroll
    for (int i = 0; i < 4; ++i) av[i] = *(const bf16x8*)(ap + k0 + (sq * 4 + i) * 8);
    if (ng < N) {
#pragma unroll
      for (int i = 0; i < 4; ++i) bv[i] = *(const bf16x8*)(bp + k0 + (sq * 4 + i) * 8);
    } else {
#pragma unroll
      for (int i = 0; i < 4; ++i) bv[i] = (bf16x8){0, 0, 0, 0, 0, 0, 0, 0};
    }
    __syncthreads();  // prior-tile LDS reads done before overwrite
#pragma unroll
    for (int i = 0; i < 4; ++i) {
      const int s = sq * 4 + i;
      *(bf16x8*)(As + srow * 128 + ((s ^ rx) * 8)) = av[i];
      *(bf16x8*)(Bs + srow * 128 + ((s ^ rx) * 8)) = bv[i];
    }
    __syncthreads();
#pragma unroll
    for (int ks = 0; ks < 4; ++ks) {
      const int u = ks * 4 + fs;
      bf16x8 a0 = *(const bf16x8*)(As + ar0 * 128 + ((u ^ (ar0 & 7)) * 8));
      bf16x8 a1 = *(const bf16x8*)(As + ar1 * 128 + ((u ^ (ar1 & 7)) * 8));
      bf16x8 b0 = *(const bf16x8*)(Bs + bc0 * 128 + ((u ^ (bc0 & 7)) * 8));
      bf16x8 b1 = *(const bf16x8*)(Bs + bc1 * 128 + ((u ^ (bc1 & 7)) * 8));
      acc[0][0] = __builtin_amdgcn_mfma_f32_16x16x32_bf16(a0, b0, acc[0][0], 0, 0, 0);
      acc[0][1] = __builtin_amdgcn_mfma_f32_16x16x32_bf16(a0, b1, acc[0][1], 0, 0, 0);
      acc[1][0] = __builtin_amdgcn_mfma_f32_16x16x32_bf16(a1, b0, acc[1][0], 0, 0, 0);
      acc[1][1] = __builtin_amdgcn_mfma_f32_16x16x32_bf16(a1, b1, acc[1][1], 0, 0, 0);
    }
  }

#pragma unroll
  for (int n = 0; n < 2; ++n) {
    const int col = bn * 64 + wc * 32 + n * 16 + fr;
    if (col < N) {
      const float bvv = (bz == 0) ? bias[col] : 0.f;
#pragma unroll
      for (int m = 0; m < 2; ++m) {
        const int rbase = bm * 64 + wr * 32 + m * 16 + fs * 4;
#pragma unroll
        for (int j = 0; j < 4; ++j) {
          float v = acc[m][n][j] + bvv;
          if (ACT == 1) v = fmaxf(v, 0.f);
          if (OUTBF) {
            Cb[(size_t)(rbase + j) * N + col] = (short)f2bf(v);
          } else {
            Cf[(size_t)(bz * M + rbase + j) * N + col] = v;
          }
        }
      }
    }
  }

  // coalesced V^T epilogue for qkv tiles covering cols [512,768)
  if (VT && bn >= 8) {
    short* tr = As;  // reuse LDS: [64 cols][68 rows]
    __syncthreads();
#pragma unroll
    for (int n = 0; n < 2; ++n) {
      const int c = wc * 32 + n * 16 + fr;
      const float bvv = bias[bn * 64 + c];
#pragma unroll
      for (int m = 0; m < 2; ++m)
#pragma unroll
        for (int j = 0; j < 4; ++j) {
          const int r = wr * 32 + m * 16 + fs * 4 + j;
          tr[c * 68 + r] = (short)f2bf(acc[m][n][j] + bvv);
        }
    }
    __syncthreads();
    const int tx = t & 63, ty = t >> 6;
    const int d0 = bn * 64 - 512, rb = bm * 64;
#pragma unroll
    for (int r = 0; r < 16; ++r) {
      const int d = ty * 16 + r;
      vtg[(size_t)(d0 + d) * 2048 + rb + tx] = tr[d * 68 + tx];
    }
  }
}

// ---------------- attention: one independent wave per (16-row graph-aligned q-tile, head) ----------------
// No LDS, no barriers. Swapped QK^T (mfma(K,Q) -> S^T): lane (fr,fs) holds
// P[q=fr][j=jbase+jt*16+fs*4+jj]; softmax over j = reg-reduce + shfl_xor(16,32).
// That layout IS the PV A-fragment; V^T global loads use the same k->j map.
__global__ __launch_bounds__(256) void attn_direct(
    const short* __restrict__ qkv, const short* __restrict__ vtg,
    const int* __restrict__ meta, short* __restrict__ out) {
  const int wid = blockIdx.x * 4 + (threadIdx.x >> 6);
  const int tile = wid >> 3, h = wid & 7;
  if (tile >= meta[0]) return;
  const int lane = threadIdx.x & 63;
  const int fr = lane & 15, fs = lane >> 4;
  const int q0 = meta[1 + tile * 3];
  const int js = meta[2 + tile * 3];
  const int je = meta[3 + tile * 3];
  const int jbase = js & ~15;
  const int njt = (je - jbase + 15) >> 4;  // <=16 (graph <=241 nodes)
  const float scale = 0.17677669529663687f;  // 1/sqrt(32)

  const int qrow = min(q0 + fr, 2047);
  const bf16x8 qf = *(const bf16x8*)(qkv + (size_t)qrow * 768 + h * 32 + fs * 8);
  const int jeq = (q0 + fr < je) ? je : 0;

  f32x4 s[16];
#pragma unroll
  for (int jt = 0; jt < 16; ++jt)
    s[jt] = (f32x4){-3.0e38f, -3.0e38f, -3.0e38f, -3.0e38f};

#pragma unroll
  for (int jt = 0; jt < 16; ++jt) {
    if (jt < njt) {
      const int krow = min(jbase + jt * 16 + fr, 2047);
      const bf16x8 kf = *(const bf16x8*)(qkv + (size_t)krow * 768 + 256 + h * 32 + fs * 8);
      s[jt] = __builtin_amdgcn_mfma_f32_16x16x32_bf16(
          kf, qf, (f32x4){0.f, 0.f, 0.f, 0.f}, 0, 0, 0);
    }
  }
  float mx = -3.0e38f;
#pragma unroll
  for (int jt = 0; jt < 16; ++jt) {
    if (jt < njt) {
#pragma unroll
      for (int jj = 0; jj < 4; ++jj) {
        const int j = jbase + jt * 16 + fs * 4 + jj;
        const bool valid = (j >= js) && (j < jeq);
        s[jt][jj] = valid ? s[jt][jj] * scale : -3.0e38f;
        mx = fmaxf(mx, s[jt][jj]);
      }
    }
  }
  mx = fmaxf(mx, __shfl_xor(mx, 16, 64));
  mx = fmaxf(mx, __shfl_xor(mx, 32, 64));
  float l = 0.f;
#pragma unroll
  for (int jt = 0; jt < 16; ++jt) {
#pragma unroll
    for (int jj = 0; jj < 4; ++jj) {
      const float p = __expf(s[jt][jj] - mx);
      s[jt][jj] = p;
      l += p;
    }
  }
  l += __shfl_xor(l, 16, 64);
  l += __shfl_xor(l, 32, 64);

  f32x4 oa[2];
  oa[0] = (f32x4){0.f, 0.f, 0.f, 0.f};
  oa[1] = (f32x4){0.f, 0.f, 0.f, 0.f};
#pragma unroll
  for (int p2 = 0; p2 < 8; ++p2) {
    if (p2 * 2 < njt) {
      bf16x8 pa;
      pa[0] = (short)f2bf(s[p2 * 2][0]);     pa[1] = (short)f2bf(s[p2 * 2][1]);
      pa[2] = (short)f2bf(s[p2 * 2][2]);     pa[3] = (short)f2bf(s[p2 * 2][3]);
      pa[4] = (short)f2bf(s[p2 * 2 + 1][0]); pa[5] = (short)f2bf(s[p2 * 2 + 1][1]);
      pa[6] = (short)f2bf(s[p2 * 2 + 1][2]); pa[7] = (short)f2bf(s[p2 * 2 + 1][3]);
      const int jb0 = min(jbase + p2 * 32 + fs * 4, 2044);
      const int jb1 = min(jbase + p2 * 32 + 16 + fs * 4, 2044);
#pragma unroll
      for (int nt = 0; nt < 2; ++nt) {
        const short* vrow = vtg + (size_t)(h * 32 + nt * 16 + fr) * 2048;
        const short4 v0 = *(const short4*)(vrow + jb0);
        const short4 v1 = *(const short4*)(vrow + jb1);
        bf16x8 vf;
        vf[0] = v0.x; vf[1] = v0.y; vf[2] = v0.z; vf[3] = v0.w;
        vf[4] = v1.x; vf[5] = v1.y; vf[6] = v1.z; vf[7] = v1.w;
        oa[nt] = __builtin_amdgcn_mfma_f32_16x16x32_bf16(pa, vf, oa[nt], 0, 0, 0);
      }
    }
  }
#pragma unroll
  for (int jj = 0; jj < 4; ++jj) {
    const float lq = __shfl(l, fs * 4 + jj, 64);
    const int node = q0 + fs * 4 + jj;
    if (node < je) {
      const float inv = 1.f / lq;
      out[(size_t)node * 256 + h * 32 + fr] = (short)f2bf(oa[0][jj] * inv);
      out[(size_t)node * 256 + h * 32 + 16 + fr] = (short)f2bf(oa[1][jj] * inv);
    }
  }
}

// ---------------- fused residual + P-partial sum + LayerNorm; writes f32 + bf16 ----------------
template <int P>
__global__ __launch_bounds__(256) void ln_kernel(
    const float* __restrict__ base, const float* __restrict__ delta,
    const float* __restrict__ s, const float* __restrict__ b,
    float* __restrict__ outf, short* __restrict__ outb) {
  const int row = blockIdx.x * 4 + (threadIdx.x >> 6);
  const int lane = threadIdx.x & 63;
  const float4 xa = *(const float4*)(base + (size_t)row * 256 + lane * 4);
  float4 v = xa;
#pragma unroll
  for (int p = 0; p < P; ++p) {
    const float4 xb = *(const float4*)(delta + (size_t)(p * 2048 + row) * 256 + lane * 4);
    v.x += xb.x; v.y += xb.y; v.z += xb.z; v.w += xb.w;
  }
  float sum = wave_sum64(v.x + v.y + v.z + v.w);
  const float mean = sum * (1.f / 256.f);
  float4 d = make_float4(v.x - mean, v.y - mean, v.z - mean, v.w - mean);
  float sq = wave_sum64(d.x * d.x + d.y * d.y + d.z * d.z + d.w * d.w);
  const float rs = rsqrtf(sq * (1.f / 256.f) + 1e-5f);
  const float4 sv = *(const float4*)(s + lane * 4);
  const float4 bv = *(const float4*)(b + lane * 4);
  float4 o = make_float4(d.x * rs * sv.x + bv.x, d.y * rs * sv.y + bv.y,
                         d.z * rs * sv.z + bv.z, d.w * rs * sv.w + bv.w);
  *(float4*)(outf + (size_t)row * 256 + lane * 4) = o;
  short4 ob;
  ob.x = (short)f2bf(o.x); ob.y = (short)f2bf(o.y);
  ob.z = (short)f2bf(o.z); ob.w = (short)f2bf(o.w);
  *(short4*)(outb + (size_t)row * 256 + lane * 4) = ob;
}

// ---------------- lat head: GEMM (N=32, K=256) + fused row-normalize ----------------
__global__ __launch_bounds__(256) void lat_kernel(
    const short* __restrict__ A, const short* __restrict__ Bt,
    const float* __restrict__ bias, float* __restrict__ out) {
  __shared__ short As[64 * 128];
  __shared__ short Bs[64 * 128];
  const int t = threadIdx.x;
  const int bm = blockIdx.x;
  const int srow = t >> 2, sq = t & 3;
  const int lane = t & 63, w = t >> 6;
  const int fr = lane & 15, fs = lane >> 4;
  const int rx = srow & 7;

  f32x4 acc[2];
  acc[0] = (f32x4){0.f, 0.f, 0.f, 0.f};
  acc[1] = (f32x4){0.f, 0.f, 0.f, 0.f};
  const short* ap = A + (size_t)(bm * 64 + srow) * 256;
  const short* bp = Bt + (size_t)srow * 256;
  const int ar = w * 16 + fr;

  for (int k0 = 0; k0 < 256; k0 += 128) {
    bf16x8 av[4], bv[4];
#pragma unroll
    for (int i = 0; i < 4; ++i) av[i] = *(const bf16x8*)(ap + k0 + (sq * 4 + i) * 8);
    if (srow < 32) {
#pragma unroll
      for (int i = 0; i < 4; ++i) bv[i] = *(const bf16x8*)(bp + k0 + (sq * 4 + i) * 8);
    } else {
#pragma unroll
      for (int i = 0; i < 4; ++i) bv[i] = (bf16x8){0, 0, 0, 0, 0, 0, 0, 0};
    }
    __syncthreads();
#pragma unroll
    for (int i = 0; i < 4; ++i) {
      const int s = sq * 4 + i;
      *(bf16x8*)(As + srow * 128 + ((s ^ rx) * 8)) = av[i];
      *(bf16x8*)(Bs + srow * 128 + ((s ^ rx) * 8)) = bv[i];
    }
    __syncthreads();
#pragma unroll
    for (int ks = 0; ks < 4; ++ks) {
      const int u = ks * 4 + fs;
      bf16x8 a0 = *(const bf16x8*)(As + ar * 128 + ((u ^ (ar & 7)) * 8));
      bf16x8 b0 = *(const bf16x8*)(Bs + fr * 128 + ((u ^ (fr & 7)) * 8));
      bf16x8 b1 = *(const bf16x8*)(Bs + (16 + fr) * 128 + ((u ^ ((16 + fr) & 7)) * 8));
      acc[0] = __builtin_amdgcn_mfma_f32_16x16x32_bf16(a0, b0, acc[0], 0, 0, 0);
      acc[1] = __builtin_amdgcn_mfma_f32_16x16x32_bf16(a0, b1, acc[1], 0, 0, 0);
    }
  }
  const float b0v = bias[fr], b1v = bias[16 + fr];
#pragma unroll
  for (int j = 0; j < 4; ++j) {
    const int row = bm * 64 + w * 16 + fs * 4 + j;
    float v0 = acc[0][j] + b0v;
    float v1 = acc[1][j] + b1v;
    float ss = v0 * v0 + v1 * v1;
    ss += __shfl_xor(ss, 1, 64);
    ss += __shfl_xor(ss, 2, 64);
    ss += __shfl_xor(ss, 4, 64);
    ss += __shfl_xor(ss, 8, 64);
    const float inv = 5.656854249492381f / fmaxf(sqrtf(ss), 1e-12f);
    out[(size_t)row * 32 + fr] = v0 * inv;
    out[(size_t)row * 32 + 16 + fr] = v1 * inv;
  }
}

// ---------------- beta head fully fused: sigmoid(relu(h@W1+b1)@w2+b2), 16 rows/block ----------------
__global__ __launch_bounds__(256) void gemm_beta(
    const short* __restrict__ A, const short* __restrict__ Bt,
    const float* __restrict__ b1b, const float* __restrict__ w2,
    const float* __restrict__ b2b, float* __restrict__ beta) {
  __shared__ float red[64];
  const int t = threadIdx.x, lane = t & 63, w = t >> 6;
  const int fr = lane & 15, fs = lane >> 4;
  const int rb = blockIdx.x * 16;

  f32x4 acc[2];
  acc[0] = (f32x4){0.f, 0.f, 0.f, 0.f};
  acc[1] = (f32x4){0.f, 0.f, 0.f, 0.f};
  const short* ap = A + (size_t)(rb + fr) * 256;
  const short* bp = Bt + (size_t)(w * 32 + fr) * 256;
  for (int k0 = 0; k0 < 256; k0 += 32) {
    const bf16x8 af = *(const bf16x8*)(ap + k0 + fs * 8);
#pragma unroll
    for (int n = 0; n < 2; ++n) {
      const bf16x8 bf = *(const bf16x8*)(bp + (size_t)n * 16 * 256 + k0 + fs * 8);
      acc[n] = __builtin_amdgcn_mfma_f32_16x16x32_bf16(af, bf, acc[n], 0, 0, 0);
    }
  }
  const int c0 = w * 32 + fr, c1 = c0 + 16;
  const float b0 = b1b[c0], b1 = b1b[c1];
  const float w0 = w2[c0], w1 = w2[c1];
  float part[4];
#pragma unroll
  for (int j = 0; j < 4; ++j) {
    const float d0 = fmaxf(acc[0][j] + b0, 0.f);
    const float d1 = fmaxf(acc[1][j] + b1, 0.f);
    part[j] = d0 * w0 + d1 * w1;
#pragma unroll
    for (int m = 1; m <= 8; m <<= 1) part[j] += __shfl_xor(part[j], m, 64);
  }
  if (fr == 0) {
#pragma unroll
    for (int j = 0; j < 4; ++j) red[w * 16 + fs * 4 + j] = part[j];
  }
  __syncthreads();
  if (t < 16) {
    const float S = red[t] + red[16 + t] + red[32 + t] + red[48 + t] + b2b[0];
    float sgm = 1.f / (1.f + __expf(-S));
    sgm = fminf(fmaxf(sgm, 1e-6f), 1.f - 1e-6f);
    beta[rb + t] = sgm;
  }
}

// ---------------- launch ----------------
extern "C" void kernel_launch(void* const* d_in, const int* in_sizes, int n_in,
                              void* d_out, int out_size, void* d_ws, size_t ws_size,
                              hipStream_t stream) {
  const int N = 2048, D = 256, FF = 1024, L = 4;

  const float* x     = (const float*)d_in[0];
  const int*   batch = (const int*)d_in[2];
  const float* Wi    = (const float*)d_in[3];
  const float* bi    = (const float*)d_in[4];
  const float* qkv_w = (const float*)d_in[5];
  const float* qkv_b = (const float*)d_in[6];
  const float* out_w = (const float*)d_in[7];
  const float* out_b = (const float*)d_in[8];
  const float* ff1_w = (const float*)d_in[9];
  const float* ff1_b = (const float*)d_in[10];
  const float* ff2_w = (const float*)d_in[11];
  const float* ff2_b = (const float*)d_in[12];
  const float* ln1_s = (const float*)d_in[13];
  const float* ln1_b = (const float*)d_in[14];
  const float* ln2_s = (const float*)d_in[15];
  const float* ln2_b = (const float*)d_in[16];
  const float* lat_w = (const float*)d_in[17];
  const float* lat_b = (const float*)d_in[18];
  const float* b1_w  = (const float*)d_in[19];
  const float* b1_b  = (const float*)d_in[20];
  const float* b2_w  = (const float*)d_in[21];
  const float* b2_b  = (const float*)d_in[22];

  float* ws = (float*)d_ws;
  float* h      = ws;                              // N*D f32
  float* tmp    = h + (size_t)N * D;               // 4*N*D f32 (split-K partials)
  int*  starts  = (int*)(tmp + (size_t)4 * N * D); // 32 ints
  int*  meta    = starts + 32;                     // 448 ints
  short* hb     = (short*)(meta + 448);            // N*D bf16
  short* qkvb   = hb + (size_t)N * D;              // N*3D bf16
  short* attnb  = qkvb + (size_t)N * 3 * D;        // N*D bf16
  short* ffb    = attnb + (size_t)N * D;           // N*FF bf16
  short* vtg    = ffb + (size_t)N * FF;            // 256*2048 bf16 (V^T per layer)
  short* qkv_t  = vtg + (size_t)256 * 2048;
  short* out_t  = qkv_t + (size_t)L * 768 * 256;
  short* ff1_t  = out_t + (size_t)L * 256 * 256;
  short* ff2_t  = ff1_t + (size_t)L * 1024 * 256;
  short* b1_t   = ff2_t + (size_t)L * 256 * 1024;
  short* lat_t  = b1_t + (size_t)128 * 256;

  float* beta_out = (float*)d_out;
  float* lat_out  = beta_out + N;

  pack_weights<<<3113, 256, 0, stream>>>(qkv_w, out_w, ff1_w, ff2_w, b1_w, lat_w,
                                         qkv_t, out_t, ff1_t, ff2_t, b1_t, lat_t,
                                         batch, starts, meta);
  inproj_kernel<<<N, 256, 0, stream>>>(x, Wi, bi, h, hb);

  for (int l = 0; l < L; ++l) {
    // qkv = h @ qkv_w + b -> bf16 (+ coalesced V^T epilogue)
    gemm_bf16<0, 1, 1><<<dim3(12, 32, 1), 256, 0, stream>>>(
        hb, qkv_t + (size_t)l * 768 * 256, qkv_b + (size_t)l * 768,
        nullptr, qkvb, vtg, N, 768, 256, 256);
    // attention (independent waves)
    attn_direct<<<288, 256, 0, stream>>>(qkvb, vtg, meta, attnb);
    // out-proj, split-K=2 -> f32 partials
    gemm_bf16<0, 0, 0><<<dim3(4, 32, 2), 256, 0, stream>>>(
        attnb, out_t + (size_t)l * 256 * 256, out_b + (size_t)l * 256,
        tmp, nullptr, nullptr, N, 256, 256, 128);
    ln_kernel<2><<<N / 4, 256, 0, stream>>>(h, tmp, ln1_s + (size_t)l * D,
                                            ln1_b + (size_t)l * D, h, hb);
    // ff1 = relu(h @ ff1_w + b) -> bf16
    gemm_bf16<1, 1, 0><<<dim3(16, 32, 1), 256, 0, stream>>>(
        hb, ff1_t + (size_t)l * FF * 256, ff1_b + (size_t)l * FF,
        nullptr, ffb, nullptr, N, FF, 256, 256);
    // ff2, split-K=4 -> f32 partials
    gemm_bf16<0, 0, 0><<<dim3(4, 32, 4), 256, 0, stream>>>(
        ffb, ff2_t + (size_t)l * 256 * FF, ff2_b + (size_t)l * 256,
        tmp, nullptr, nullptr, N, 256, 1024, 256);
    ln_kernel<4><<<N / 4, 256, 0, stream>>>(h, tmp, ln2_s + (size_t)l * D,
                                            ln2_b + (size_t)l * D, h, hb);
  }

  lat_kernel<<<N / 64, 256, 0, stream>>>(hb, lat_t, lat_b, lat_out);
  gemm_beta<<<128, 256, 0, stream>>>(hb, b1_t, b1_b, b2_w, b2_b, beta_out);
}